// Round 1
// baseline (347.693 us; speedup 1.0000x reference)
//
#include <hip/hip_runtime.h>

#define NUM_INST 64
#define SLOT_STRIDE 11                      // 8 sums + sumsq + count = 10, pad to 11 (gcd(11,32)=1)
#define ACC_FLOATS (NUM_INST * SLOT_STRIDE) // 704
#define NWAVES 4
#define BLOCK 256
#define GRID 1024

__global__ __launch_bounds__(BLOCK) void vsl_main(const float4* __restrict__ rows,
                                                  const int* __restrict__ labels,
                                                  float* __restrict__ gacc, int n) {
    __shared__ float acc[NWAVES][ACC_FLOATS];
    const int tid = threadIdx.x;
    const int wid = tid >> 6;

    float* accf = &acc[0][0];
    for (int j = tid; j < NWAVES * ACC_FLOATS; j += BLOCK) accf[j] = 0.0f;
    __syncthreads();

    const int stride = GRID * BLOCK;
    for (int i = blockIdx.x * BLOCK + tid; i < n; i += stride) {
        const int lbl = labels[i];
        const float4 a = rows[2 * i];
        const float4 b = rows[2 * i + 1];
        const float sq = a.x * a.x + a.y * a.y + a.z * a.z + a.w * a.w +
                         b.x * b.x + b.y * b.y + b.z * b.z + b.w * b.w;
        float* base = &acc[wid][lbl * SLOT_STRIDE];
        atomicAdd(base + 0, a.x);
        atomicAdd(base + 1, a.y);
        atomicAdd(base + 2, a.z);
        atomicAdd(base + 3, a.w);
        atomicAdd(base + 4, b.x);
        atomicAdd(base + 5, b.y);
        atomicAdd(base + 6, b.z);
        atomicAdd(base + 7, b.w);
        atomicAdd(base + 8, sq);
        atomicAdd(base + 9, 1.0f);
    }
    __syncthreads();

    for (int j = tid; j < ACC_FLOATS; j += BLOCK) {
        float v = acc[0][j] + acc[1][j] + acc[2][j] + acc[3][j];
        if (v != 0.0f) atomicAdd(&gacc[j], v);  // pad/empty slots skip the global atomic
    }
}

__global__ __launch_bounds__(64) void vsl_final(const float* __restrict__ gacc,
                                                float* __restrict__ out) {
    const int s = threadIdx.x;  // one thread per instance, 1 wave
    float val = 0.0f;
    const float* base = &gacc[s * SLOT_STRIDE];
    const float cnt = base[9];
    if (s != 0 && cnt > 0.0f) {
        const float ss = base[8];
        float m2 = 0.0f;
#pragma unroll
        for (int d = 0; d < 8; ++d) {
            const float sd = base[d];
            m2 += sd * sd;
        }
        val = (ss - m2 / cnt) / (cnt * 8.0f);
    }
#pragma unroll
    for (int off = 32; off > 0; off >>= 1) val += __shfl_down(val, off, 64);
    if (s == 0) out[0] = val;
}

extern "C" void kernel_launch(void* const* d_in, const int* in_sizes, int n_in,
                              void* d_out, int out_size, void* d_ws, size_t ws_size,
                              hipStream_t stream) {
    const float* variances = (const float*)d_in[0];  // [N, 8] fp32
    const int* labels = (const int*)d_in[1];         // [N] int32
    const int n = in_sizes[1];                       // N
    float* gacc = (float*)d_ws;                      // 704 floats of scratch

    hipMemsetAsync(d_ws, 0, ACC_FLOATS * sizeof(float), stream);
    vsl_main<<<GRID, BLOCK, 0, stream>>>((const float4*)variances, labels, gacc, n);
    vsl_final<<<1, 64, 0, stream>>>(gacc, (float*)d_out);
}

// Round 2
// 209.744 us; speedup vs baseline: 1.6577x; 1.6577x over previous
//
#include <hip/hip_runtime.h>

#define NUM_INST 64
#define SLOT 12      // floats per routing slot: 8 used, stride 48B keeps 16B alignment
#define BLOCK 256
#define NWAVES 4
#define GRID 1024

__global__ __launch_bounds__(BLOCK) void vsl_main(const float4* __restrict__ rows,
                                                  const int* __restrict__ labels,
                                                  float* __restrict__ gacc, int n) {
    // per-wave private routing buffer: 64 slots x 12 floats (no cross-wave sharing -> no barriers)
    __shared__ float lds[NWAVES][NUM_INST * SLOT];
    const int tid = threadIdx.x;
    const int w = tid >> 6;
    const int lane = tid & 63;

    // lane d of each wave owns label d: accumulate its stats in registers
    float s0 = 0, s1 = 0, s2 = 0, s3 = 0, s4 = 0, s5 = 0, s6 = 0, s7 = 0;
    float ssq = 0, cntf = 0;

    float* slotbase = &lds[w][lane * SLOT];
    const int stride = GRID * BLOCK;

    for (int i = blockIdx.x * BLOCK + tid;; i += stride) {
        const bool valid = (i < n);
        const unsigned long long bv = __ballot(valid);
        if (!bv) break;

        int lbl = 0;
        float4 a = {0, 0, 0, 0}, b = {0, 0, 0, 0};
        if (valid) {
            lbl = labels[i];
            a = rows[2 * i];
            b = rows[2 * i + 1];
        }

        // publish my element to my private slot (plain DS writes, conflict-free-ish)
        *(float4*)(slotbase) = a;
        *(float4*)(slotbase + 4) = b;

        // 6 ballots on label bits -> mask of source lanes whose label == my lane id
        unsigned long long m = bv;
#pragma unroll
        for (int bpos = 0; bpos < 6; ++bpos) {
            const unsigned long long bb = __ballot((lbl >> bpos) & 1);
            m &= ((lane >> bpos) & 1) ? bb : ~bb;
        }
        cntf += (float)__popcll(m);  // exact integer counts, no atomic

        // ensure slot writes are visible before gathering (same-wave DS is in-order;
        // the memory clobber stops compiler reordering)
        asm volatile("s_waitcnt lgkmcnt(0)" ::: "memory");

        while (m) {
            const int s = (int)__builtin_ctzll(m);
            m &= m - 1;
            const float* sp = &lds[w][s * SLOT];
            const float4 p = *(const float4*)sp;
            const float4 q = *(const float4*)(sp + 4);
            s0 += p.x; s1 += p.y; s2 += p.z; s3 += p.w;
            s4 += q.x; s5 += q.y; s6 += q.z; s7 += q.w;
            ssq += p.x * p.x + p.y * p.y + p.z * p.z + p.w * p.w +
                   q.x * q.x + q.y * q.y + q.z * q.z + q.w * q.w;
        }
    }

    // flush: reuse the routing buffer for the per-wave totals (own region, own wave -> safe)
    float* fb = &lds[w][lane * SLOT];
    fb[0] = s0; fb[1] = s1; fb[2] = s2; fb[3] = s3;
    fb[4] = s4; fb[5] = s5; fb[6] = s6; fb[7] = s7;
    fb[8] = ssq; fb[9] = cntf;
    __syncthreads();

    // cross-wave reduce + one global atomic per (label, stat) per block
    for (int j = tid; j < NUM_INST * 10; j += BLOCK) {
        const int lbl = j / 10;
        const int st = j - lbl * 10;
        float v = 0;
#pragma unroll
        for (int ww = 0; ww < NWAVES; ++ww) v += lds[ww][lbl * SLOT + st];
        atomicAdd(&gacc[j], v);
    }
}

__global__ __launch_bounds__(64) void vsl_final(const float* __restrict__ gacc,
                                                float* __restrict__ out) {
    const int s = threadIdx.x;  // one thread per instance, 1 wave
    float val = 0.0f;
    const float* base = &gacc[s * 10];
    const float cnt = base[9];
    if (s != 0 && cnt > 0.0f) {
        const float ss = base[8];
        float m2 = 0.0f;
#pragma unroll
        for (int d = 0; d < 8; ++d) {
            const float sd = base[d];
            m2 += sd * sd;
        }
        val = (ss - m2 / cnt) / (cnt * 8.0f);
    }
#pragma unroll
    for (int off = 32; off > 0; off >>= 1) val += __shfl_down(val, off, 64);
    if (s == 0) out[0] = val;
}

extern "C" void kernel_launch(void* const* d_in, const int* in_sizes, int n_in,
                              void* d_out, int out_size, void* d_ws, size_t ws_size,
                              hipStream_t stream) {
    const float* variances = (const float*)d_in[0];  // [N, 8] fp32
    const int* labels = (const int*)d_in[1];         // [N] int32
    const int n = in_sizes[1];                       // N
    float* gacc = (float*)d_ws;                      // 640 floats of scratch

    hipMemsetAsync(d_ws, 0, NUM_INST * 10 * sizeof(float), stream);
    vsl_main<<<GRID, BLOCK, 0, stream>>>((const float4*)variances, labels, gacc, n);
    vsl_final<<<1, 64, 0, stream>>>(gacc, (float*)d_out);
}